// Round 12
// baseline (457.274 us; speedup 1.0000x reference)
//
#include <hip/hip_runtime.h>
#include <cmath>
#include <cstdint>
#include <cstddef>

typedef unsigned long long u64;
typedef unsigned int u32;

#define NPX   2500
#define NANCH 22500
#define PRE_TOPK 10000
#define NWORDS 160      // 160*64 = 10240 bits per NMS row

struct AnchorBase { float b[36]; };

typedef __attribute__((ext_vector_type(8))) short bf16x8;
typedef __attribute__((ext_vector_type(4))) float f32x4;

__device__ inline unsigned short f2bf(float f) {
    u32 u = __float_as_uint(f);
    u32 r = u + 0x7fffu + ((u >> 16) & 1u);
    return (unsigned short)(r >> 16);
}
__device__ inline float bf2f(unsigned short h) {
    return __uint_as_float(((u32)h) << 16);
}

// ---------------------------------------------------------------------------
// KPREP: fused input prep (Xt bf16 hi/lo padded grid; W' bf16 hi/lo).
// ---------------------------------------------------------------------------
__global__ __launch_bounds__(256) void kprep(const float* __restrict__ feat,
                                             const float* __restrict__ wr,
                                             unsigned short* __restrict__ xthi,
                                             unsigned short* __restrict__ xtlo,
                                             unsigned short* __restrict__ whi,
                                             unsigned short* __restrict__ wlo)
{
    __shared__ float sh[4608];
    int bid = blockIdx.x;
    int t = threadIdx.x;
    if (bid < 416) {
        float (*tile)[65] = (float(*)[65])sh;
        int gr = bid >> 3;          // grid row 0..51
        int cc = bid & 7;           // c-chunk
        int tx = t & 63, ty = t >> 6;
        int y = gr - 1;
        bool rowok = (gr >= 1) && (gr <= 50);
#pragma unroll
        for (int i = 0; i < 16; ++i) {
            int c = i * 4 + ty;
            tile[c][tx] = (rowok && tx < 50)
                        ? feat[(size_t)(cc * 64 + c) * NPX + y * 50 + tx] : 0.f;
        }
        __syncthreads();
#pragma unroll
        for (int i = 0; i < 16; ++i) {
            int xp = i * 4 + ty;
            int cell = gr * 64 + xp;
            bool ok = rowok && xp >= 1 && xp <= 50;
            float v = ok ? tile[tx][xp - 1] : 0.f;
            unsigned short hi = f2bf(v);
            xthi[(size_t)cell * 512 + cc * 64 + tx] = hi;
            xtlo[(size_t)cell * 512 + cc * 64 + tx] = f2bf(v - bf2f(hi));
        }
    } else {
        int oc = bid - 416;         // 0..511
        for (int j = t; j < 4608; j += 256) sh[j] = wr[(size_t)oc * 4608 + j];
        __syncthreads();
        for (int k = t; k < 4608; k += 256) {
            int c = k & 511, tap = k >> 9;
            float v = sh[c * 9 + tap];
            unsigned short hi = f2bf(v);
            whi[(size_t)oc * 4608 + k] = hi;
            wlo[(size_t)oc * 4608 + k] = f2bf(v - bf2f(hi));
        }
    }
}

// ---------------------------------------------------------------------------
// K1m v7: LDS-staged MFMA GEMM (R11 — unchanged this round).
// ---------------------------------------------------------------------------
__global__ __launch_bounds__(256) void k1m(const unsigned short* __restrict__ xthi,
                                           const unsigned short* __restrict__ xtlo,
                                           const unsigned short* __restrict__ whi,
                                           const unsigned short* __restrict__ wlo,
                                           float* __restrict__ pk,
                                           int cptLog, int cptm1, int cptMul, int niter)
{
    __shared__ __align__(16) unsigned short Ah[8192];   // 128oc x 64k
    __shared__ __align__(16) unsigned short Al[8192];
    __shared__ __align__(16) unsigned short Bh[4096];   // 64px x 64k
    __shared__ __align__(16) unsigned short Bl[4096];

    int t = threadIdx.x;
    int lane = t & 63, wave = t >> 6;
    int wo = wave & 1, wp = wave >> 1;
    int ocb = blockIdx.x, pxb = blockIdx.y, bs = blockIdx.z;
    int q = lane >> 4, m = lane & 15;
    int c0base = bs * cptMul;

    int g  = t & 7;
    int r0 = t >> 3;                     // 0..31
    int ocA[4];
    int cellB[2];
#pragma unroll
    for (int i = 0; i < 4; ++i) ocA[i] = ocb * 128 + r0 + 32 * i;
#pragma unroll
    for (int i = 0; i < 2; ++i) {
        int opx = pxb * 64 + r0 + 32 * i;
        cellB[i] = (opx < NPX) ? ((opx / 50) + 1) * 64 + (opx % 50) + 1 : 190;
    }

    f32x4 acc[8];
    f32x4 zf = {0.f, 0.f, 0.f, 0.f};
#pragma unroll
    for (int i = 0; i < 8; ++i) acc[i] = zf;

    for (int it = 0; it < niter; ++it) {
        int tap = it >> cptLog;
        int cw  = it & cptm1;
        int c0  = c0base + cw * 64;
        int t3  = (tap * 43) >> 7;                      // tap/3
        int tapoff = (t3 - 1) * 64 + (tap - t3 * 3) - 1;
#pragma unroll
        for (int i = 0; i < 4; ++i) {
            int rl = r0 + 32 * i;
            int la = rl * 64 + g * 8;
            size_t ga = (size_t)ocA[i] * 4608 + tap * 512 + c0 + g * 8;
            *(bf16x8*)(Ah + la) = *(const bf16x8*)(whi + ga);
            *(bf16x8*)(Al + la) = *(const bf16x8*)(wlo + ga);
        }
#pragma unroll
        for (int i = 0; i < 2; ++i) {
            int rl = r0 + 32 * i;
            int la = rl * 64 + g * 8;
            size_t gb = (size_t)(cellB[i] + tapoff) * 512 + c0 + g * 8;
            *(bf16x8*)(Bh + la) = *(const bf16x8*)(xthi + gb);
            *(bf16x8*)(Bl + la) = *(const bf16x8*)(xtlo + gb);
        }
        __syncthreads();
#pragma unroll
        for (int ks = 0; ks < 2; ++ks) {
            bf16x8 fah[4], fal[4], fbh[2], fbl[2];
#pragma unroll
            for (int mt = 0; mt < 4; ++mt) {
                int off = (wo * 64 + mt * 16 + m) * 64 + ks * 32 + q * 8;
                fah[mt] = *(const bf16x8*)(Ah + off);
                fal[mt] = *(const bf16x8*)(Al + off);
            }
#pragma unroll
            for (int nt = 0; nt < 2; ++nt) {
                int off = (wp * 32 + nt * 16 + m) * 64 + ks * 32 + q * 8;
                fbh[nt] = *(const bf16x8*)(Bh + off);
                fbl[nt] = *(const bf16x8*)(Bl + off);
            }
#pragma unroll
            for (int mt = 0; mt < 4; ++mt)
#pragma unroll
                for (int nt = 0; nt < 2; ++nt) {
                    f32x4 a = acc[mt * 2 + nt];
                    a = __builtin_amdgcn_mfma_f32_16x16x32_bf16(fal[mt], fbh[nt], a, 0, 0, 0);
                    a = __builtin_amdgcn_mfma_f32_16x16x32_bf16(fah[mt], fbl[nt], a, 0, 0, 0);
                    a = __builtin_amdgcn_mfma_f32_16x16x32_bf16(fah[mt], fbh[nt], a, 0, 0, 0);
                    acc[mt * 2 + nt] = a;
                }
        }
        __syncthreads();
    }
#pragma unroll
    for (int mt = 0; mt < 4; ++mt)
#pragma unroll
        for (int nt = 0; nt < 2; ++nt)
#pragma unroll
            for (int r = 0; r < 4; ++r) {
                int oc = ocb * 128 + wo * 64 + mt * 16 + q * 4 + r;
                int px = pxb * 64 + wp * 32 + nt * 16 + m;
                pk[((size_t)bs * 512 + oc) * 2560 + px] = acc[mt * 2 + nt][r];
            }
}

// ---------------------------------------------------------------------------
// K2a: fused k-split reduce + bias + ReLU + 1x1 heads partial GEMM.
// ---------------------------------------------------------------------------
__global__ __launch_bounds__(256) void k2a_heads(const float* __restrict__ pk, int ns,
                                                 const float* __restrict__ br,
                                                 const float* __restrict__ wcls,
                                                 const float* __restrict__ wreg,
                                                 float* __restrict__ part)
{
    __shared__ float vt[64 * 64];
    __shared__ float Wl[45 * 64];
    int t  = threadIdx.x;
    int pb = blockIdx.x;           // 0..39
    int s  = blockIdx.y;           // 0..7
    int cb = s * 64;
    for (int e = t; e < 45 * 64; e += 256) {
        int u = e >> 6, c = e & 63;
        Wl[e] = (u < 9) ? wcls[u * 512 + cb + c] : wreg[(u - 9) * 512 + cb + c];
    }
    int pxl = t & 63, ug = t >> 6;
    int px = pb * 64 + pxl;
    bool ok = px < NPX;
#pragma unroll
    for (int i = 0; i < 16; ++i) {
        int c = ug * 16 + i;       // wave-uniform
        float v = 0.f;
        if (ok) {
            size_t bidx = (size_t)(cb + c) * 2560 + px;
            v = br[cb + c];
            for (int ks = 0; ks < ns; ++ks) v += pk[(size_t)ks * 512 * 2560 + bidx];
            v = v > 0.f ? v : 0.f;
        }
        vt[c * 64 + pxl] = v;
    }
    __syncthreads();
    int ubase = ug * 12;
    int ulim  = (45 - ubase < 12) ? (45 - ubase) : 12;
    float acc[12];
#pragma unroll
    for (int j = 0; j < 12; ++j) acc[j] = 0.f;
    for (int c = 0; c < 64; ++c) {
        float v = vt[c * 64 + pxl];
#pragma unroll
        for (int j = 0; j < 12; ++j)
            acc[j] = fmaf(v, Wl[(ubase + j) * 64 + c], acc[j]);
    }
    if (ok) {
        for (int j = 0; j < ulim; ++j)
            part[((size_t)s * 45 + ubase + j) * NPX + px] = acc[j];
    }
}

// ---------------------------------------------------------------------------
// K2b: reduce partials + bias, sigmoid, decode, clip, validity, sort key.
// ---------------------------------------------------------------------------
__global__ __launch_bounds__(256) void k2b_decode(const float* __restrict__ part,
                                                  const float* __restrict__ bcls,
                                                  const float* __restrict__ breg,
                                                  AnchorBase ab,
                                                  float* __restrict__ score,
                                                  float* __restrict__ bx1, float* __restrict__ by1,
                                                  float* __restrict__ bx2, float* __restrict__ by2,
                                                  u32* __restrict__ valid,
                                                  u64* __restrict__ key)
{
    int id = blockIdx.x * 256 + threadIdx.x;
    if (id >= NANCH) return;
    int k  = id / NPX;
    int px = id - k * NPX;

    float z  = bcls[k];
    float d0 = breg[k * 4 + 0], d1 = breg[k * 4 + 1];
    float d2 = breg[k * 4 + 2], d3 = breg[k * 4 + 3];
#pragma unroll
    for (int s = 0; s < 8; ++s) {
        const float* p = part + (size_t)s * 45 * NPX;
        z  += p[(size_t)k * NPX + px];
        d0 += p[(size_t)(9 + k * 4 + 0) * NPX + px];
        d1 += p[(size_t)(9 + k * 4 + 1) * NPX + px];
        d2 += p[(size_t)(9 + k * 4 + 2) * NPX + px];
        d3 += p[(size_t)(9 + k * 4 + 3) * NPX + px];
    }
    float sc = 1.f / (1.f + expf(-z));

    int yy = px / 50, xx = px - (px / 50) * 50;
    float fx = (float)xx, fy = (float)yy;
    float ax1 = fx + ab.b[k * 4 + 0], ay1 = fy + ab.b[k * 4 + 1];
    float ax2 = fx + ab.b[k * 4 + 2], ay2 = fy + ab.b[k * 4 + 3];
    float aw = ax2 - ax1, ah = ay2 - ay1;
    float cx = ax1 + 0.5f * aw, cy = ay1 + 0.5f * ah;
    float pcx = d0 * aw + cx, pcy = d1 * ah + cy;
    float pw = expf(d2) * aw, ph = expf(d3) * ah;
    float x1 = pcx - 0.5f * pw, y1 = pcy - 0.5f * ph;
    float x2 = pcx + 0.5f * pw, y2 = pcy + 0.5f * ph;
    x1 = fminf(fmaxf(x1, 0.f), 800.f);
    y1 = fminf(fmaxf(y1, 0.f), 800.f);
    x2 = fminf(fmaxf(x2, 0.f), 800.f);
    y2 = fminf(fmaxf(y2, 0.f), 800.f);
    u32 v = ((x2 - x1) >= 16.f) && ((y2 - y1) >= 16.f);

    int f = px * 9 + k;
    score[f] = sc;
    bx1[f] = x1; by1[f] = y1; bx2[f] = x2; by2[f] = y2;
    valid[f] = v;
    u32 sb = __float_as_uint(sc);
    key[f] = ((u64)(~sb) << 32) | (u32)f;
}

// ---------------------------------------------------------------------------
// K3a v4: partial ranks, 8-way i-register-blocking x 20 j-chunks of 1126
// (pad = ~0ull, never < any real key). DS traffic /2 vs R10, spread over
// 220 blocks -> lands at the ~13us VALU floor instead of 22us DS-bound.
// ---------------------------------------------------------------------------
__global__ __launch_bounds__(256) void k3a_rank(const u64* __restrict__ key,
                                                u32* __restrict__ rankp)
{
    __shared__ __align__(16) u64 sk[1126];
    int t  = threadIdx.x;
    int jb = blockIdx.y;           // 0..19
    for (int e = t; e < 1126; e += 256) {
        int gj = jb * 1126 + e;
        sk[e] = (gj < NANCH) ? key[gj] : ~0ull;
    }
    __syncthreads();
    int ib = blockIdx.x * 2048 + t;     // 11*2048 = 22528
    u64 k0[8];
    u32 cnt[8];
#pragma unroll
    for (int r = 0; r < 8; ++r) {
        int i = ib + r * 256;
        k0[r] = (i < NANCH) ? key[i] : 0ull;
        cnt[r] = 0;
    }
    const ulonglong2* sk2 = (const ulonglong2*)sk;
#pragma unroll 5
    for (int j = 0; j < 563; ++j) {
        ulonglong2 v = sk2[j];
#pragma unroll
        for (int r = 0; r < 8; ++r) {
            cnt[r] += (v.x < k0[r]) ? 1u : 0u;
            cnt[r] += (v.y < k0[r]) ? 1u : 0u;
        }
    }
    size_t base = (size_t)jb * NANCH;
#pragma unroll
    for (int r = 0; r < 8; ++r) {
        int i = ib + r * 256;
        if (i < NANCH) rankp[base + i] = cnt[r];
    }
}

// ---------------------------------------------------------------------------
// K3b: sum 20 partial ranks, scatter top-10000 (+ packed float4 boxes);
// sInv[r] = 1 if invalid box.
// ---------------------------------------------------------------------------
__global__ __launch_bounds__(256) void k3b_gather(const u32* __restrict__ rankp,
                                                  const float* __restrict__ score,
                                                  const float* __restrict__ bx1, const float* __restrict__ by1,
                                                  const float* __restrict__ bx2, const float* __restrict__ by2,
                                                  const u32* __restrict__ valid,
                                                  float* __restrict__ sS,
                                                  float* __restrict__ sx1, float* __restrict__ sy1,
                                                  float* __restrict__ sx2, float* __restrict__ sy2,
                                                  float4* __restrict__ sbox4,
                                                  u32* __restrict__ sInv)
{
    int i = blockIdx.x * 256 + threadIdx.x;
    if (i >= NANCH) return;
    u32 r = 0;
#pragma unroll
    for (int c = 0; c < 20; ++c) r += rankp[(size_t)c * NANCH + i];
    if (r >= PRE_TOPK) return;
    float x1 = bx1[i], y1 = by1[i], x2 = bx2[i], y2 = by2[i];
    sS[r] = score[i];
    sx1[r] = x1; sy1[r] = y1; sx2[r] = x2; sy2[r] = y2;
    float4 b4; b4.x = x1; b4.y = y1; b4.z = x2; b4.w = y2;
    sbox4[r] = b4;
    sInv[r] = valid[i] ? 0u : 1u;
}

// ---------------------------------------------------------------------------
// K4 v5: row-per-wave suppression matrix, 4 i-rows per wave sharing one
// j-stream (sbox4 L2 traffic /4 vs R10's 780MB). Loop starts at the group's
// diagonal word; rows with later diagonals skip stores there (memset covers).
// ---------------------------------------------------------------------------
__global__ __launch_bounds__(256) void k4_mat(const float4* __restrict__ sbox4,
                                              u64* __restrict__ rows,
                                              u64* __restrict__ selfw)
{
    int t = threadIdx.x, lane = t & 63, wave = t >> 6;
    int ig = (blockIdx.x * 4 + wave) * 4;       // 625 blocks -> ig 0..9996
    float4 bi[4];
    float  ai[4];
    int    wd[4];
    u64    dm[4];
#pragma unroll
    for (int r = 0; r < 4; ++r) {
        int i = ig + r;
        bi[r] = sbox4[i];                       // wave-uniform, once
        ai[r] = (bi[r].z - bi[r].x) * (bi[r].w - bi[r].y);
        wd[r] = i >> 6;
        int ish = i & 63;
        dm[r] = ~((2ull << ish) - 1ull);
    }
    for (int w = wd[0]; w < 157; ++w) {
        float4 bj = sbox4[(w << 6) + lane];     // coalesced, shared by 4 rows
        float aj = (bj.z - bj.x) * (bj.w - bj.y);
#pragma unroll
        for (int r = 0; r < 4; ++r) {
            if (w < wd[r]) continue;            // uniform branch
            float xx1 = fmaxf(bi[r].x, bj.x);
            float yy1 = fmaxf(bi[r].y, bj.y);
            float xx2 = fminf(bi[r].z, bj.z);
            float yy2 = fminf(bi[r].w, bj.w);
            float iw = fmaxf(xx2 - xx1, 0.f);
            float ih = fmaxf(yy2 - yy1, 0.f);
            float inter = iw * ih;
            float uni = ai[r] + aj - inter;
            u64 b = __ballot(inter > 0.7f * uni);
            if (w == wd[r]) b &= dm[r];
            if (w == 156)   b &= 0xFFFFull;
            if (lane == 0) {
                rows[(size_t)(ig + r) * NWORDS + w] = b;
                if (w == wd[r]) selfw[ig + r] = b;
            }
        }
    }
}

// ---------------------------------------------------------------------------
// K5a: remLow = OR of rows[j] over all VALID j (parallel). Upper-triangular
// rows make F(S) = valid & ~OR(rows[j in S]) an exact "suppressed by earlier
// member of S" test — no ordering needed.
// ---------------------------------------------------------------------------
__global__ __launch_bounds__(256) void k5a_orall(const u64* __restrict__ rows,
                                                 const u32* __restrict__ sInv,
                                                 u64* __restrict__ remLow)
{
    int t = threadIdx.x, lane = t & 63, wave = t >> 6;
    int wg = blockIdx.x * 4 + wave;             // 0..79, 128 j each
    u64 a0 = 0, a1 = 0, a2 = 0;
#pragma unroll
    for (int rnd = 0; rnd < 2; ++rnd) {
        int j0 = wg * 128 + rnd * 64;
        int j  = j0 + lane;
        u32 inv = (j < PRE_TOPK) ? sInv[j] : 1u;
        u64 vm = __ballot(inv == 0u);
        while (vm) {
            int k = __ffsll((unsigned long long)vm) - 1;
            vm &= vm - 1;
            const u64* rp = rows + (size_t)(j0 + k) * NWORDS;
            a0 |= rp[lane];
            a1 |= rp[64 + lane];
            if (lane < 32) a2 |= rp[128 + lane];
        }
    }
    if (a0) atomicOr((unsigned long long*)(remLow + lane), (unsigned long long)a0);
    if (a1) atomicOr((unsigned long long*)(remLow + 64 + lane), (unsigned long long)a1);
    if (lane < 32 && a2) atomicOr((unsigned long long*)(remLow + 128 + lane), (unsigned long long)a2);
}

// ---------------------------------------------------------------------------
// K5b: lower = valid & ~remLow (definitely-kept set; lower subset of keep*).
// remUp = OR of lower rows + invalid bits (the seed for the serial scan).
// lowerBM = lower as bitmap.
// ---------------------------------------------------------------------------
__global__ __launch_bounds__(256) void k5b_lower(const u64* __restrict__ rows,
                                                 const u32* __restrict__ sInv,
                                                 const u64* __restrict__ remLow,
                                                 u64* __restrict__ remUp,
                                                 u64* __restrict__ lowerBM)
{
    int t = threadIdx.x, lane = t & 63, wave = t >> 6;
    int jw = blockIdx.x * 4 + wave;             // word 0..159
    int j  = jw * 64 + lane;
    u32 inv = (j < PRE_TOPK) ? sInv[j] : 1u;
    u64 rl = remLow[jw];                        // one broadcast load per wave
    bool low = (inv == 0u) && !((rl >> lane) & 1ull);
    u64 lowm = __ballot(low);
    u64 invm = __ballot(inv != 0u);
    if (lane == 0) {
        if (lowm) atomicOr((unsigned long long*)(lowerBM + jw), (unsigned long long)lowm);
        if (invm) atomicOr((unsigned long long*)(remUp + jw), (unsigned long long)invm);
    }
    u64 a0 = 0, a1 = 0, a2 = 0;
    u64 vm = lowm;
    while (vm) {
        int k = __ffsll((unsigned long long)vm) - 1;
        vm &= vm - 1;
        const u64* rp = rows + (size_t)(jw * 64 + k) * NWORDS;
        a0 |= rp[lane];
        a1 |= rp[64 + lane];
        if (lane < 32) a2 |= rp[128 + lane];
    }
    if (a0) atomicOr((unsigned long long*)(remUp + lane), (unsigned long long)a0);
    if (a1) atomicOr((unsigned long long*)(remUp + 64 + lane), (unsigned long long)a1);
    if (lane < 32 && a2) atomicOr((unsigned long long*)(remUp + 128 + lane), (unsigned long long)a2);
}

// ---------------------------------------------------------------------------
// K5c: seeded serial NMS scan. r-state seeded with remUp (lower rows +
// invalid). Lower members are kept WITHOUT loads/selfw (their suppression
// already in seed); only undetermined keeps trigger the serial row-OR.
// Serial chain drops from ~107 loads (R11: 73us) to |kept U| loads.
// ---------------------------------------------------------------------------
__global__ __launch_bounds__(64) void k5c_scan(const u64* __restrict__ rows,
                                               const u64* __restrict__ selfw,
                                               const u64* __restrict__ remUp,
                                               const u64* __restrict__ lowerBM,
                                               const float* __restrict__ sS,
                                               const float* __restrict__ sx1, const float* __restrict__ sy1,
                                               const float* __restrict__ sx2, const float* __restrict__ sy2,
                                               float* __restrict__ out)
{
    __shared__ int keptList[2000];
    __shared__ int kcnt;
    int l = threadIdx.x;
    u64 r0 = remUp[l];
    u64 r1 = remUp[64 + l];
    u64 r2 = (l < 32) ? remUp[128 + l] : ~0ull;
    u64 lb0 = lowerBM[l];
    u64 lb1 = lowerBM[64 + l];
    u64 lb2 = (l < 32) ? lowerBM[128 + l] : 0ull;

    u64 cur[8], nxt[8];
#pragma unroll
    for (int k = 0; k < 8; ++k) cur[k] = selfw[(size_t)k * 64 + l];
#pragma unroll
    for (int k = 0; k < 8; ++k) {
        int ww = 8 + k;
        nxt[k] = (ww < 157) ? selfw[(size_t)ww * 64 + l] : 0ull;
    }

    int cnt = 0;
    bool done = false;
    for (int wg = 0; wg < 20; ++wg) {
#pragma unroll
        for (int ph = 0; ph < 8; ++ph) {
            int w = wg * 8 + ph;
            if (done || w > 156) continue;
            u64 swreg = cur[ph];
            int slot = w >> 6, owner = w & 63;
            u64 rv = (slot == 0) ? r0 : (slot == 1) ? r1 : r2;
            u64 lv = (slot == 0) ? lb0 : (slot == 1) ? lb1 : lb2;
            u64 rw = __shfl(rv, owner, 64);
            u64 lw = __shfl(lv, owner, 64);
            u64 wmask = (w == 156) ? 0xFFFFull : ~0ull;
            u64 av = (~rw) & wmask;
            u64 loadset = 0;
            while (av) {                 // resolve ascending, registers only
                int b = __ffsll((unsigned long long)av) - 1;
                u64 bit = 1ull << b;
                av &= ~bit;
                if (l == 0) keptList[cnt] = (w << 6) + b;
                cnt++;
                if (cnt >= 2000) { done = true; break; }
                if (!(lw & bit)) {       // undetermined keep: needs selfw + row
                    loadset |= bit;
                    u64 sw = __shfl(swreg, b, 64);
                    av &= ~sw;
                }
            }
            u64 kk = done ? 0ull : loadset;
            while (kk) {                 // OR undetermined-kept rows, 16/batch
                int bsx[16];
                int nb = 0;
                while (kk && nb < 16) {
                    int b = __ffsll((unsigned long long)kk) - 1;
                    kk &= kk - 1;
                    bsx[nb++] = b;
                }
                u64 a0 = 0, a1 = 0, a2 = 0;
#pragma unroll
                for (int u = 0; u < 16; ++u) {
                    if (u < nb) {
                        int i = (w << 6) + bsx[u];
                        const u64* rp = rows + (size_t)i * NWORDS;
                        a0 |= rp[l];
                        a1 |= rp[64 + l];
                        if (l < 32) a2 |= rp[128 + l];
                    }
                }
                r0 |= a0; r1 |= a1; r2 |= a2;
            }
        }
        if (!done) {
            int base = (wg + 2) * 8;
#pragma unroll
            for (int k = 0; k < 8; ++k) cur[k] = nxt[k];
#pragma unroll
            for (int k = 0; k < 8; ++k) {
                int ww = base + k;
                nxt[k] = (ww < 157) ? selfw[(size_t)ww * 64 + l] : 0ull;
            }
        }
    }
    if (l == 0) kcnt = (cnt < 2000) ? cnt : 2000;
    __syncthreads();
    int K = kcnt;
    for (int r = l; r < 2000; r += 64) {
        if (r < K) {
            int j = keptList[r];
            out[r * 4 + 0] = sx1[j];
            out[r * 4 + 1] = sy1[j];
            out[r * 4 + 2] = sx2[j];
            out[r * 4 + 3] = sy2[j];
            out[8000 + r]  = sS[j];
        } else {
            out[r * 4 + 0] = 0.f; out[r * 4 + 1] = 0.f;
            out[r * 4 + 2] = 0.f; out[r * 4 + 3] = 0.f;
            out[8000 + r]  = 0.f;
        }
    }
}

// ---------------------------------------------------------------------------
extern "C" void kernel_launch(void* const* d_in, const int* in_sizes, int n_in,
                              void* d_out, int out_size, void* d_ws, size_t ws_size,
                              hipStream_t stream)
{
    (void)in_sizes; (void)n_in; (void)out_size;
    const float* feat = (const float*)d_in[1];
    const float* wrpn = (const float*)d_in[3];
    const float* brpn = (const float*)d_in[4];
    const float* wcls = (const float*)d_in[5];
    const float* bcls = (const float*)d_in[6];
    const float* wreg = (const float*)d_in[7];
    const float* breg = (const float*)d_in[8];
    float* out = (float*)d_out;

    // K-split factor by workspace budget. need(ns) = ns*512*2560*4 + 16,252,928.
    int ns = (ws_size >= 58195968) ? 8 : (ws_size >= 37224448) ? 4 : 2;
    int cpt     = 8 / ns;
    int cptLog  = (ns == 2) ? 2 : (ns == 4) ? 1 : 0;
    int cptm1   = cpt - 1;
    int cptMul  = cpt * 64;
    int niter   = 9 * cpt;
    size_t pkB = (size_t)ns * 512 * 2560 * 4;

    char* ws = (char*)d_ws;
    float* pk = (float*)ws;
    unsigned short* Xthi = (unsigned short*)(ws + pkB);
    unsigned short* Xtlo = Xthi + (size_t)52 * 64 * 512;
    unsigned short* Whi  = (unsigned short*)(ws + pkB + 6815744);
    unsigned short* Wlo  = Whi + (size_t)512 * 4608;

    char* sm = ws + pkB;
    float* score = (float*)(sm + 0);             // 90,000
    float* bx1   = (float*)(sm + 90000);
    float* by1   = (float*)(sm + 180000);
    float* bx2   = (float*)(sm + 270000);
    float* by2   = (float*)(sm + 360000);
    u32*   valid = (u32*)  (sm + 450000);        // 90,000
    u64*   key   = (u64*)  (sm + 540000);        // 180,000
    u32*   rankp = (u32*)  (sm + 720000);        // 1,800,000 (20 chunks)
    float* sS    = (float*)(sm + 2520000);       // 40,000
    float* sx1   = (float*)(sm + 2560000);
    float* sy1   = (float*)(sm + 2600000);
    float* sx2   = (float*)(sm + 2640000);
    float* sy2   = (float*)(sm + 2680000);
    u32*   sInv  = (u32*)  (sm + 2720000);       // 40,960
    u64*   selfw = (u64*)  (sm + 2760960);       // 81,920
    float4* sbox4= (float4*)(sm + 2842880);      // 163,840
    u64*   remLow= (u64*)  (sm + 3006720);       // 1,280
    u64*   remUp = (u64*)  (sm + 3008000);       // 1,280
    u64*   lowBM = (u64*)  (sm + 3009280);       // 1,280
    float* part  = (float*)(sm + 3010560);       // 3,600,000 (k2a..k2b)
    u64*   rows  = (u64*)  (sm + 3010560);       // 12,800,000 (k4..k5c) -> ends sm+15.81M < 16.25M
    // peak footprint = pkB + 16,252,928 (ns=4 -> 37.2 MB, proven available)

    AnchorBase ab;
    {
        const float scales[3] = {128.f, 256.f, 512.f};
        const float aspect[3] = {0.5f, 1.f, 2.f};
        for (int ai = 0; ai < 3; ++ai) {
            float hr = sqrtf(aspect[ai]);
            float wratio = 1.0f / hr;
            for (int si = 0; si < 3; ++si) {
                float wsz = wratio * scales[si];
                float hsz = hr * scales[si];
                int a = ai * 3 + si;
                ab.b[a * 4 + 0] = rintf(-wsz / 2.0f);
                ab.b[a * 4 + 1] = rintf(-hsz / 2.0f);
                ab.b[a * 4 + 2] = rintf( wsz / 2.0f);
                ab.b[a * 4 + 3] = rintf( hsz / 2.0f);
            }
        }
    }

    kprep    <<<928, 256, 0, stream>>>(feat, wrpn, Xthi, Xtlo, Whi, Wlo);
    k1m      <<<dim3(4, 40, ns), 256, 0, stream>>>(Xthi, Xtlo, Whi, Wlo, pk,
                                                   cptLog, cptm1, cptMul, niter);
    k2a_heads<<<dim3(40, 8), 256, 0, stream>>>(pk, ns, brpn, wcls, wreg, part);
    k2b_decode<<<88, 256, 0, stream>>>(part, bcls, breg, ab, score, bx1, by1, bx2, by2, valid, key);
    k3a_rank <<<dim3(11, 20), 256, 0, stream>>>(key, rankp);
    k3b_gather<<<88, 256, 0, stream>>>(rankp, score, bx1, by1, bx2, by2, valid,
                                       sS, sx1, sy1, sx2, sy2, sbox4, sInv);
    hipMemsetAsync(rows, 0, (size_t)PRE_TOPK * NWORDS * 8, stream);
    hipMemsetAsync(remLow, 0, 3840, stream);     // remLow+remUp+lowBM contiguous
    k4_mat   <<<625, 256, 0, stream>>>(sbox4, rows, selfw);
    k5a_orall<<<20, 256, 0, stream>>>(rows, sInv, remLow);
    k5b_lower<<<40, 256, 0, stream>>>(rows, sInv, remLow, remUp, lowBM);
    k5c_scan <<<1, 64, 0, stream>>>(rows, selfw, remUp, lowBM,
                                    sS, sx1, sy1, sx2, sy2, out);
}